// Round 8
// baseline (3884.864 us; speedup 1.0000x reference)
//
#include <hip/hip_runtime.h>
#include <math.h>

#define B_ 4
#define G_ 16906
#define D_ 256
#define H_ 8
#define DH_ 32
#define M_ 110
#define L_ 6
#define FF_ 1024
#define NSEQ (G_ + 1)          // 16907
#define NR (B_ * NSEQ)         // 67628
#define NRP_ 67712             // 529*128, row-padded for 128-tiles
#define NYT_ 529               // row tiles
#define BH_ 32                 // B_*H_
#define QS_ 768                // fused qkv row stride (q:0, k:256, v:512)

static constexpr float SCALE_  = 0.42044820762685725f;   // 32^-0.25
static constexpr float MSCALE_ = 0.09534625892455922f;   // 110^-0.5
static constexpr float FEPS_   = 1e-4f;

// ---- static workspace (module-load-time allocation; R1 proved d_ws too small) ----
#define SZP_ ((size_t)NRP_ * D_)                 // fp32 x buffer
#define WS_FLOATS 92000000                       // ~368 MB
__device__ float g_ws[WS_FLOATS];

typedef __attribute__((ext_vector_type(8))) short bh8;   // 8 bf16 (4 VGPR)
typedef __attribute__((ext_vector_type(4))) float f4;    // MFMA acc

// ---- helpers ----
__device__ __forceinline__ unsigned f2u(float f){
    unsigned u = __float_as_uint(f);
    return (u & 0x80000000u) ? ~u : (u | 0x80000000u);
}
__device__ __forceinline__ float u2f(unsigned u){
    return (u & 0x80000000u) ? __uint_as_float(u & 0x7fffffffu) : __uint_as_float(~u);
}
__device__ __forceinline__ unsigned short f2b(float f){   // fp32 -> bf16 RNE
    unsigned u = __float_as_uint(f);
    return (unsigned short)((u + 0x7fffu + ((u >> 16) & 1u)) >> 16);
}
__device__ __forceinline__ float bf2f(unsigned short u){
    return __uint_as_float(((unsigned)u) << 16);
}
// R18: direct global->LDS DMA, 16B per lane (m97 ladder step; m151: +35% vs reg-staging)
__device__ __forceinline__ void gld16(const unsigned short* g, unsigned short* l){
    __builtin_amdgcn_global_load_lds((const __attribute__((address_space(1))) void*)g,
                                     (__attribute__((address_space(3))) void*)l, 16, 0, 0);
}

// =============== preprocess ===============
__global__ void k_pre_init(unsigned* __restrict__ maxkey){
    if (threadIdx.x == 0) *maxkey = 0x007fffffu;  // f2u(-inf)
}

__global__ void k_rowsum(const float* __restrict__ expr, float* __restrict__ ssum){
    int b = blockIdx.x, t = threadIdx.x;
    float s = 0.f;
    for (int g = t; g < G_; g += 256) s += fabsf(expr[(size_t)b * G_ + g]);
    __shared__ float red[256];
    red[t] = s; __syncthreads();
    for (int off = 128; off > 0; off >>= 1){ if (t < off) red[t] += red[t + off]; __syncthreads(); }
    if (t == 0) ssum[b] = red[0];
}

__global__ void k_compute_e(const float* __restrict__ expr, const float* __restrict__ ssum,
                            float* __restrict__ ebuf, unsigned* __restrict__ maxkey){
    int t = threadIdx.x;
    int idx = blockIdx.x * 256 + t;
    float e = -INFINITY;
    if (idx < B_ * G_){
        int b = idx / G_;
        float denom = fmaxf(ssum[b], 1e-12f);
        e = log1pf(expr[idx] / denom * 1e4f);
        ebuf[idx] = e;
    }
    __shared__ float red[256];
    red[t] = e; __syncthreads();
    for (int off = 128; off > 0; off >>= 1){ if (t < off) red[t] = fmaxf(red[t], red[t + off]); __syncthreads(); }
    if (t == 0) atomicMax(maxkey, f2u(red[0]));
}

__global__ void k_embed(const float* __restrict__ ebuf, const unsigned* __restrict__ maxkey,
                        const float* __restrict__ tokemb, const float* __restrict__ cls,
                        float* __restrict__ x){
    int row = blockIdx.x, t = threadIdx.x;
    if (row >= NR){ x[(size_t)row * D_ + t] = 0.f; return; }   // pad rows -> 0
    int b = row / NSEQ, i = row % NSEQ;
    float v;
    if (i == 0){
        v = cls[t];
    } else {
        float e = ebuf[(size_t)b * G_ + (i - 1)];
        float mx = u2f(*maxkey);
        float step = mx / 7.0f;                 // linspace(0,mx,8)[:7] = step*j
        int cnt = 0;
        #pragma unroll
        for (int j = 0; j < 7; ++j){
            float bin = step * (float)j;
            cnt += (bin < e) ? 1 : 0;           // searchsorted side='left'
        }
        if (cnt > 6) cnt = 6;
        v = tokemb[cnt * D_ + t];
    }
    x[(size_t)row * D_ + t] = v;
}

// =============== layernorm: fp32 in, bf16 out ===============
// R15: one 64-lane wave per row, shuffle-reduce — no barriers, no LDS.
__launch_bounds__(256)
__global__ void k_ln(const float* __restrict__ X, unsigned short* __restrict__ Y,
                     const float* __restrict__ g, const float* __restrict__ b){
    int wave = threadIdx.x >> 6, lane = threadIdx.x & 63;
    int row = blockIdx.x * 4 + wave;
    float4 v = *(const float4*)&X[(size_t)row * D_ + lane * 4];
    float s = v.x + v.y + v.z + v.w;
    s += __shfl_xor(s, 1);  s += __shfl_xor(s, 2);  s += __shfl_xor(s, 4);
    s += __shfl_xor(s, 8);  s += __shfl_xor(s, 16); s += __shfl_xor(s, 32);
    float mu = s * (1.0f / 256.0f);
    float d0 = v.x - mu, d1 = v.y - mu, d2 = v.z - mu, d3 = v.w - mu;
    float q = d0 * d0 + d1 * d1 + d2 * d2 + d3 * d3;
    q += __shfl_xor(q, 1);  q += __shfl_xor(q, 2);  q += __shfl_xor(q, 4);
    q += __shfl_xor(q, 8);  q += __shfl_xor(q, 16); q += __shfl_xor(q, 32);
    float inv = rsqrtf(q * (1.0f / 256.0f) + 1e-5f);
    float4 gv = *(const float4*)&g[lane * 4];
    float4 bv = *(const float4*)&b[lane * 4];
    ushort4 o;
    o.x = f2b(d0 * inv * gv.x + bv.x);
    o.y = f2b(d1 * inv * gv.y + bv.y);
    o.z = f2b(d2 * inv * gv.z + bv.z);
    o.w = f2b(d3 * inv * gv.w + bv.w);
    *(ushort4*)&Y[(size_t)row * D_ + lane * 4] = o;
}

// =============== weight transpose + bf16 convert: Wout[n][k] = Win[k][n] ===============
__global__ void k_wconv(const float* __restrict__ Win, unsigned short* __restrict__ Wout,
                        int K, int N, int lstride){
    __shared__ float tile[32][33];
    int l = blockIdx.z;
    const float* W = Win + (size_t)l * K * N;
    unsigned short* O = Wout + (size_t)l * lstride;
    int n0 = blockIdx.x * 32, k0 = blockIdx.y * 32;
    int tx = threadIdx.x, ty = threadIdx.y;
    #pragma unroll
    for (int j = 0; j < 4; ++j)
        tile[ty + j * 8][tx] = W[(size_t)(k0 + ty + j * 8) * N + n0 + tx];
    __syncthreads();
    #pragma unroll
    for (int j = 0; j < 4; ++j){
        int n = ty + j * 8;
        O[(size_t)(n0 + n) * K + k0 + tx] = f2b(tile[tx][n]);
    }
}

__global__ void k_packbias(const float* __restrict__ bq, const float* __restrict__ bk,
                           const float* __restrict__ bv, float* __restrict__ o){
    int l = blockIdx.x, t = threadIdx.x;
    o[l * QS_ + t]        = bq[l * D_ + t];
    o[l * QS_ + 256 + t]  = bk[l * D_ + t];
    o[l * QS_ + 512 + t]  = bv[l * D_ + t];
}

// =============== bf16 MFMA GEMM: C = op(A @ Wt^T + bias) ===============
// MODE 0: Cf = A@W + bias (fp32)        MODE 1: Cf += A@W + bias (fp32 residual)
// MODE 2: Cb = bf16(gelu(A@W + bias))   MODE 3: Cb = bf16(A@W + bias)
// R22: 3-buffer, 2-ahead DMA pipeline with counted vmcnt (T4, m218: counted
//      vmcnt vs drain-0 = +38-73%). Raw s_barrier (no compiler vmcnt(0) drain,
//      m201 precedent); vmcnt(4) in main loop keeps next stage's 4 loads in
//      flight across the barrier. Per-wave vmcnt(4) BEFORE the barrier =>
//      all waves' cur-buffer loads landed when any wave proceeds. WAR safe:
//      reads of overwritten buffer completed behind prior iteration's
//      lgkmcnt-before-MFMA waits, which precede this barrier in program order.
#define ABUF_SH 4096           // one 128x32 bf16 tile, in shorts (8 KB)
#define TBUF_SH 8192           // A tile + B tile per stage, in shorts (16 KB)
#define EPIT 136
template <int MODE>
__launch_bounds__(256)
__global__ void gemm_bf16(const unsigned short* __restrict__ A,
                          const unsigned short* __restrict__ Wt,
                          const float* __restrict__ bias,
                          float* __restrict__ Cf, unsigned short* __restrict__ Cb,
                          int K, int N, int NY){
    int NX = N >> 7;
    int lid = blockIdx.x;
    int xcd = lid & 7, slot = lid >> 3;
    int colt = slot % NX;
    int rowt = (slot / NX) * 8 + xcd;
    if (rowt >= NY) return;
    int rowBase = rowt * 128, colBase = colt * 128;

    __shared__ __align__(16) unsigned short smem[3 * TBUF_SH];   // 48 KB
    int tid = threadIdx.x;
    int lane = tid & 63, wave = tid >> 6;
    int wrow = (wave >> 1) * 64, wcol = (wave & 1) * 64;
    int m = lane & 15, kg = lane >> 4;

    // staging: thread t owns LDS slot (row = t>>2, 16B-chunk c = t&3), dest is
    // linear (base + t*16B). Slot (r,c) holds GLOBAL chunk c ^ ((r>>1)&3).
    int sr = tid >> 2, sc = tid & 3;
    int scs = sc ^ ((sr >> 1) & 3);
    const unsigned short* Ag = A  + (size_t)(rowBase + sr) * K + scs * 8;
    const unsigned short* Bg = Wt + (size_t)(colBase + sr) * K + scs * 8;
    // read-side swizzle: want chunk kg of row (..+m); base row mult of 16 -> use m only
    int kc8 = (kg ^ ((m >> 1) & 3)) * 8;

    f4 acc[4][4];
    #pragma unroll
    for (int i = 0; i < 4; ++i)
        #pragma unroll
        for (int j = 0; j < 4; ++j) acc[i][j] = (f4){0.f, 0.f, 0.f, 0.f};

    auto stage = [&](int sel, int it){
        unsigned short* sb = smem + sel * TBUF_SH;
        int k0 = it << 5;
        gld16(Ag + k0,                  sb + (tid << 3));
        gld16(Ag + (size_t)64 * K + k0, sb + 2048 + (tid << 3));
        gld16(Bg + k0,                  sb + ABUF_SH + (tid << 3));
        gld16(Bg + (size_t)64 * K + k0, sb + ABUF_SH + 2048 + (tid << 3));
    };

    const int NIT = K >> 5;          // >= 8 for all call sites
    stage(0, 0);
    stage(1, 1);
    int cur = 0;
    for (int it = 0; it < NIT; ++it){
        // buffer cur's 4 loads must have landed; the newer stage's 4 may remain
        // in flight (never drain to 0 in the main loop — T4).
        if (it + 1 < NIT) asm volatile("s_waitcnt vmcnt(4)" ::: "memory");
        else              asm volatile("s_waitcnt vmcnt(0)" ::: "memory");
        __builtin_amdgcn_s_barrier();
        __builtin_amdgcn_sched_barrier(0);
        if (it + 2 < NIT){
            int nxt = cur + 2; if (nxt >= 3) nxt -= 3;
            stage(nxt, it + 2);
        }
        const unsigned short* sb = smem + cur * TBUF_SH;
        bh8 af[4], bf[4];
        #pragma unroll
        for (int mi = 0; mi < 4; ++mi)
            af[mi] = *(const bh8*)&sb[(wrow + mi * 16 + m) * 32 + kc8];
        #pragma unroll
        for (int ni = 0; ni < 4; ++ni)
            bf[ni] = *(const bh8*)&sb[ABUF_SH + (wcol + ni * 16 + m) * 32 + kc8];
        #pragma unroll
        for (int mi = 0; mi < 4; ++mi)
            #pragma unroll
            for (int ni = 0; ni < 4; ++ni)
                acc[mi][ni] = __builtin_amdgcn_mfma_f32_16x16x32_bf16(af[mi], bf[ni], acc[mi][ni], 0, 0, 0);
        ++cur; if (cur >= 3) cur = 0;
    }
    __syncthreads();
    int q4 = lane >> 4;
    if (MODE == 0 || MODE == 1){
        #pragma unroll
        for (int ni = 0; ni < 4; ++ni){
            int col = colBase + wcol + ni * 16 + m;
            float bv = bias[col];
            #pragma unroll
            for (int mi = 0; mi < 4; ++mi){
                int r0 = rowBase + wrow + mi * 16 + q4 * 4;
                #pragma unroll
                for (int rg = 0; rg < 4; ++rg){
                    int row = r0 + rg;
                    float v = acc[mi][ni][rg] + bv;
                    if (MODE == 1) v += Cf[(size_t)row * N + col];
                    Cf[(size_t)row * N + col] = v;
                }
            }
        }
    } else {
        #pragma unroll
        for (int half = 0; half < 2; ++half){
            if ((wrow >> 6) == half){
                #pragma unroll
                for (int ni = 0; ni < 4; ++ni){
                    int coll = wcol + ni * 16 + m;
                    float bv = bias[colBase + coll];
                    #pragma unroll
                    for (int mi = 0; mi < 4; ++mi){
                        int rl0 = (wrow & 63) + mi * 16 + q4 * 4;
                        #pragma unroll
                        for (int rg = 0; rg < 4; ++rg){
                            float v = acc[mi][ni][rg] + bv;
                            if (MODE == 2) v = 0.5f * v * (1.0f + erff(v * 0.70710678118654752f));
                            smem[(rl0 + rg) * EPIT + coll] = f2b(v);
                        }
                    }
                }
            }
            __syncthreads();
            #pragma unroll
            for (int p = 0; p < 4; ++p){
                int idx = p * 256 + tid;
                int r = idx >> 4, ch = idx & 15;
                int grow = rowBase + half * 64 + r;
                uint4 val = *(const uint4*)&smem[r * EPIT + ch * 8];
                *(uint4*)&Cb[(size_t)grow * N + colBase + ch * 8] = val;
            }
            __syncthreads();
        }
    }
}

// =============== attention state init ===============
__global__ void k_layer_init(float* __restrict__ kfsum, float* __restrict__ ctx,
                             unsigned* __restrict__ stab){
    int t = blockIdx.x * 256 + threadIdx.x;
    int nt = gridDim.x * 256;
    if (t == 0) *stab = 0x007fffffu;  // f2u(-inf)
    for (int i = t; i < BH_ * M_; i += nt) kfsum[i] = 0.f;
    for (int i = t; i < BH_ * M_ * DH_; i += nt) ctx[i] = 0.f;
}

// ---- k_kmax (R19 per-wave structure + R21 diagk restored from register frags) ----
__launch_bounds__(256)
__global__ void k_kmax(const unsigned short* __restrict__ qkv, const float* __restrict__ proj,
                       unsigned* __restrict__ stab, float* __restrict__ diagk){
    __shared__ __align__(16) unsigned short pjT[112 * 40];
    __shared__ float red[256];
    int t = threadIdx.x, lane = t & 63, wave = t >> 6;
    int m16 = lane & 15, quad = lane >> 4;
    int bh = blockIdx.y, b = bh >> 3, hh = bh & 7;
    for (int e = t; e < 112 * 32; e += 256){
        int mm = e >> 5, d = e & 31;
        pjT[mm * 40 + d] = f2b((mm < M_) ? SCALE_ * proj[mm * DH_ + d] : 0.f);
    }
    __syncthreads();
    bh8 pj[7];
    #pragma unroll
    for (int nt = 0; nt < 7; ++nt)
        pj[nt] = *(const bh8*)&pjT[(nt * 16 + m16) * 40 + quad * 8];
    int i0 = blockIdx.x * 256, i1 = min(i0 + 256, NSEQ);
    float mx = -INFINITY;
    for (int t0 = i0 + wave * 32; t0 < i1; t0 += 128){
        int rows = min(32, i1 - t0);
        size_t rb = (size_t)(b * NSEQ + t0);
        bh8 a0 = *(const bh8*)(qkv + (rb + m16) * QS_ + 256 + hh * DH_ + quad * 8);
        bh8 a1 = *(const bh8*)(qkv + (rb + 16 + m16) * QS_ + 256 + hh * DH_ + quad * 8);
        // R21: diagk from register fragments (per-lane 8-elem sum + shfl over quads)
        {
            float s0 = 0.f, s1 = 0.f;
            const unsigned short* p0 = (const unsigned short*)&a0;
            const unsigned short* p1 = (const unsigned short*)&a1;
            #pragma unroll
            for (int j = 0; j < 8; ++j){
                float x0 = bf2f(p0[j]); s0 += x0 * x0;
                float x1 = bf2f(p1[j]); s1 += x1 * x1;
            }
            s0 += __shfl_xor(s0, 16); s0 += __shfl_xor(s0, 32);
            s1 += __shfl_xor(s1, 16); s1 += __shfl_xor(s1, 32);
            if (quad == 0){
                if (m16 < rows)
                    diagk[(rb + m16) * 8 + hh]      = 0.5f * SCALE_ * SCALE_ * s0;
                if (16 + m16 < rows)
                    diagk[(rb + 16 + m16) * 8 + hh] = 0.5f * SCALE_ * SCALE_ * s1;
            }
        }
        #pragma unroll
        for (int nt = 0; nt < 7; ++nt){
            int f = nt * 16 + m16;
            f4 d0 = (f4){0.f,0.f,0.f,0.f}, d1 = (f4){0.f,0.f,0.f,0.f};
            d0 = __builtin_amdgcn_mfma_f32_16x16x32_bf16(a0, pj[nt], d0, 0, 0, 0);
            d1 = __builtin_amdgcn_mfma_f32_16x16x32_bf16(a1, pj[nt], d1, 0, 0, 0);
            if (f < M_){
                #pragma unroll
                for (int rg = 0; rg < 4; ++rg){
                    int r0 = quad * 4 + rg;
                    if (r0 < rows)      mx = fmaxf(mx, d0[rg]);
                    if (r0 + 16 < rows) mx = fmaxf(mx, d1[rg]);
                }
            }
        }
    }
    red[t] = mx; __syncthreads();
    for (int off = 128; off > 0; off >>= 1){ if (t < off) red[t] = fmaxf(red[t], red[t + off]); __syncthreads(); }
    if (t == 0) atomicMax(stab, f2u(red[0]));
}

// ---- k_kv: R0 block-cooperative version (proven ≤146 µs; R19/R20 per-wave
// rewrites measured 238/247 µs — reverted, see R21 post-mortem) ----
__launch_bounds__(256)
__global__ void k_kv(const unsigned short* __restrict__ qkv,
                     const float* __restrict__ proj, const float* __restrict__ diagk,
                     const unsigned* __restrict__ stabkey,
                     float* __restrict__ kfsum, float* __restrict__ ctx){
    __shared__ __align__(16) unsigned short pjT[112 * 40];
    __shared__ __align__(16) unsigned short kl[32 * 40];
    __shared__ __align__(16) unsigned short vT[32 * 40];
    __shared__ __align__(16) unsigned short kfT[112 * 40];
    __shared__ float diagl[32];
    int t = threadIdx.x, lane = t & 63, wave = t >> 6;
    int m16 = lane & 15, quad = lane >> 4;
    int bh = blockIdx.y, b = bh >> 3, hh = bh & 7;
    for (int e = t; e < 112 * 32; e += 256){
        int mm = e >> 5, d = e & 31;
        pjT[mm * 40 + d] = f2b((mm < M_) ? SCALE_ * proj[mm * DH_ + d] : 0.f);
    }
    float stab = u2f(*stabkey);
    f4 acc[2][2];
    #pragma unroll
    for (int i = 0; i < 2; ++i)
        #pragma unroll
        for (int j = 0; j < 2; ++j) acc[i][j] = (f4){0.f,0.f,0.f,0.f};
    float ksum = 0.f;
    int i0 = blockIdx.x * 256, i1 = min(i0 + 256, NSEQ);
    int sr = t >> 2, sl = t & 3;
    __syncthreads();
    for (int t0 = i0; t0 < i1; t0 += 32){
        int rows = min(32, i1 - t0);
        if (t < 128){
            size_t base = ((size_t)(b * NSEQ + t0 + sr)) * QS_ + hh * DH_ + sl * 8;
            uint4 kv = (uint4){0,0,0,0}, vv = (uint4){0,0,0,0};
            if (sr < rows){
                kv = *(const uint4*)(qkv + base + 256);
                vv = *(const uint4*)(qkv + base + 512);
            }
            *(uint4*)&kl[sr * 40 + sl * 8] = kv;
            const unsigned short* vs = (const unsigned short*)&vv;
            #pragma unroll
            for (int j = 0; j < 8; ++j)
                vT[(sl * 8 + j) * 40 + sr] = vs[j];
        }
        if (t < 32) diagl[t] = (t < rows) ? diagk[((size_t)(b * NSEQ + t0 + t)) * 8 + hh] : 0.f;
        __syncthreads();
        #pragma unroll
        for (int nn = 0; nn < 2; ++nn){
            int nt = wave + nn * 4;
            if (nt >= 7) continue;
            bh8 bfrag = *(const bh8*)&pjT[(nt * 16 + m16) * 40 + quad * 8];
            int f = nt * 16 + m16;
            #pragma unroll
            for (int mt = 0; mt < 2; ++mt){
                bh8 afrag = *(const bh8*)&kl[(mt * 16 + m16) * 40 + quad * 8];
                f4 dd = (f4){0.f,0.f,0.f,0.f};
                dd = __builtin_amdgcn_mfma_f32_16x16x32_bf16(afrag, bfrag, dd, 0, 0, 0);
                #pragma unroll
                for (int rg = 0; rg < 4; ++rg){
                    int r = mt * 16 + quad * 4 + rg;
                    float kf = 0.f;
                    if (r < rows) kf = MSCALE_ * (__expf(dd[rg] - diagl[r] - stab) + FEPS_);
                    kfT[f * 40 + r] = f2b(kf);
                }
            }
        }
        __syncthreads();
        #pragma unroll
        for (int mm = 0; mm < 2; ++mm){
            int mt = wave + mm * 4;
            if (mt >= 7) continue;
            bh8 afrag = *(const bh8*)&kfT[(mt * 16 + m16) * 40 + quad * 8];
            #pragma unroll
            for (int nt2 = 0; nt2 < 2; ++nt2){
                bh8 bfrag = *(const bh8*)&vT[(nt2 * 16 + m16) * 40 + quad * 8];
                acc[mm][nt2] = __builtin_amdgcn_mfma_f32_16x16x32_bf16(afrag, bfrag, acc[mm][nt2], 0, 0, 0);
            }
        }
        if (t < M_){
            for (int i = 0; i < rows; ++i) ksum += bf2f(kfT[t * 40 + i]);
        }
        __syncthreads();
    }
    float* ctx_bh = ctx + (size_t)bh * M_ * DH_;
    #pragma unroll
    for (int mm = 0; mm < 2; ++mm){
        int mt = wave + mm * 4;
        if (mt >= 7) continue;
        #pragma unroll
        for (int nt2 = 0; nt2 < 2; ++nt2){
            #pragma unroll
            for (int rg = 0; rg < 4; ++rg){
                int f = mt * 16 + quad * 4 + rg;
                int dh = nt2 * 16 + m16;
                if (f < M_) atomicAdd(&ctx_bh[f * DH_ + dh], acc[mm][nt2][rg]);
            }
        }
    }
    if (t < M_) atomicAdd(&kfsum[bh * M_ + t], ksum);
}

// ---- k_qattn: R19 per-wave version (rowmax via shfl, wave-private qf slab,
// no inner barriers) ----
#define CXP 136
__launch_bounds__(256)
__global__ void k_qattn(const unsigned short* __restrict__ qkv, const float* __restrict__ proj,
                        const float* __restrict__ kfsumg,
                        const float* __restrict__ ctxg, unsigned short* __restrict__ Ob){
    __shared__ __align__(16) unsigned short pjT[112 * 40];
    __shared__ __align__(16) unsigned short cxT[32 * CXP];     // [dh][f], zero-padded f>=M_
    __shared__ __align__(16) unsigned short qfs[4][32 * CXP];  // per-wave qf slab
    int t = threadIdx.x, lane = t & 63, wave = t >> 6;
    int m16 = lane & 15, quad = lane >> 4;
    int bh = blockIdx.y, b = bh >> 3, hh = bh & 7;
    const float* ctx_bh = ctxg + (size_t)bh * M_ * DH_;
    for (int e = t; e < 112 * 32; e += 256){
        int mm = e >> 5, d = e & 31;
        pjT[mm * 40 + d] = f2b((mm < M_) ? SCALE_ * proj[mm * DH_ + d] : 0.f);
    }
    for (int e = t; e < 32 * 128; e += 256){
        int dh = e >> 7, f = e & 127;
        cxT[dh * CXP + f] = f2b((f < M_) ? ctx_bh[f * DH_ + dh] : 0.f);
    }
    // zero qf slab cols 112..127 once (never written by f-tiles; avoids NaN garbage)
    {
        unsigned short* qw = &qfs[wave][0];
        int r = lane & 31, c0 = 112 + (lane >> 5) * 8;
        #pragma unroll
        for (int j = 0; j < 8; ++j) qw[r * CXP + c0 + j] = 0;
    }
    __syncthreads();
    float kfsr[7];
    #pragma unroll
    for (int nt = 0; nt < 7; ++nt){
        int f = nt * 16 + m16;
        kfsr[nt] = (f < M_) ? kfsumg[bh * M_ + f] : 0.f;
    }
    bh8 cxf[2][4];
    #pragma unroll
    for (int dt = 0; dt < 2; ++dt)
        #pragma unroll
        for (int kk = 0; kk < 4; ++kk)
            cxf[dt][kk] = *(const bh8*)&cxT[(dt * 16 + m16) * CXP + kk * 32 + quad * 8];
    unsigned short* qw = &qfs[wave][0];
    int i0 = blockIdx.x * 256, i1 = min(i0 + 256, NSEQ);
    for (int t0 = i0 + wave * 32; t0 < i1; t0 += 128){
        int rows = min(32, i1 - t0);
        size_t rb = (size_t)(b * NSEQ + t0);
        bh8 a0 = *(const bh8*)(qkv + (rb + m16) * QS_ + hh * DH_ + quad * 8);
        bh8 a1 = *(const bh8*)(qkv + (rb + 16 + m16) * QS_ + hh * DH_ + quad * 8);
        float s0 = 0.f, s1 = 0.f;
        {
            const unsigned short* p0 = (const unsigned short*)&a0;
            const unsigned short* p1 = (const unsigned short*)&a1;
            #pragma unroll
            for (int j = 0; j < 8; ++j){
                float x0 = bf2f(p0[j]); s0 += x0 * x0;
                float x1 = bf2f(p1[j]); s1 += x1 * x1;
            }
            s0 += __shfl_xor(s0, 16); s0 += __shfl_xor(s0, 32);
            s1 += __shfl_xor(s1, 16); s1 += __shfl_xor(s1, 32);
            s0 *= 0.5f * SCALE_ * SCALE_;
            s1 *= 0.5f * SCALE_ * SCALE_;
        }
        f4 dv0[7], dv1[7];
        #pragma unroll
        for (int nt = 0; nt < 7; ++nt){
            bh8 pjf = *(const bh8*)&pjT[(nt * 16 + m16) * 40 + quad * 8];
            f4 d0 = (f4){0.f,0.f,0.f,0.f}, d1 = (f4){0.f,0.f,0.f,0.f};
            dv0[nt] = __builtin_amdgcn_mfma_f32_16x16x32_bf16(a0, pjf, d0, 0, 0, 0);
            dv1[nt] = __builtin_amdgcn_mfma_f32_16x16x32_bf16(a1, pjf, d1, 0, 0, 0);
        }
        // per-row max over f: in-lane over nt (guard f<M_), then shfl over m16
        float rm0[4], rm1[4];
        #pragma unroll
        for (int rg = 0; rg < 4; ++rg){ rm0[rg] = -INFINITY; rm1[rg] = -INFINITY; }
        #pragma unroll
        for (int nt = 0; nt < 7; ++nt){
            if (nt * 16 + m16 < M_){
                #pragma unroll
                for (int rg = 0; rg < 4; ++rg){
                    rm0[rg] = fmaxf(rm0[rg], dv0[nt][rg]);
                    rm1[rg] = fmaxf(rm1[rg], dv1[nt][rg]);
                }
            }
        }
        #pragma unroll
        for (int rg = 0; rg < 4; ++rg){
            float v = rm0[rg];
            v = fmaxf(v, __shfl_xor(v, 1)); v = fmaxf(v, __shfl_xor(v, 2));
            v = fmaxf(v, __shfl_xor(v, 4)); v = fmaxf(v, __shfl_xor(v, 8));
            rm0[rg] = v;
            v = rm1[rg];
            v = fmaxf(v, __shfl_xor(v, 1)); v = fmaxf(v, __shfl_xor(v, 2));
            v = fmaxf(v, __shfl_xor(v, 4)); v = fmaxf(v, __shfl_xor(v, 8));
            rm1[rg] = v;
        }
        float dg0[4], dg1[4];
        #pragma unroll
        for (int rg = 0; rg < 4; ++rg){
            dg0[rg] = __shfl(s0, quad * 4 + rg);
            dg1[rg] = __shfl(s1, quad * 4 + rg);
        }
        // qf -> slab [r][f]; den partials in-lane
        float den0[4], den1[4];
        #pragma unroll
        for (int rg = 0; rg < 4; ++rg){ den0[rg] = 0.f; den1[rg] = 0.f; }
        #pragma unroll
        for (int nt = 0; nt < 7; ++nt){
            int f = nt * 16 + m16;
            #pragma unroll
            for (int rg = 0; rg < 4; ++rg){
                int r0 = quad * 4 + rg;
                float q0 = 0.f, q1 = 0.f;
                if (f < M_){
                    q0 = MSCALE_ * (__expf(dv0[nt][rg] - dg0[rg] - rm0[rg]) + FEPS_);
                    q1 = MSCALE_ * (__expf(dv1[nt][rg] - dg1[rg] - rm1[rg]) + FEPS_);
                }
                qw[r0 * CXP + f]        = f2b(q0);
                qw[(16 + r0) * CXP + f] = f2b(q1);
                den0[rg] += q0 * kfsr[nt];
                den1[rg] += q1 * kfsr[nt];
            }
        }
        #pragma unroll
        for (int rg = 0; rg < 4; ++rg){
            float v = den0[rg];
            v += __shfl_xor(v, 1); v += __shfl_xor(v, 2);
            v += __shfl_xor(v, 4); v += __shfl_xor(v, 8);
            den0[rg] = v;
            v = den1[rg];
            v += __shfl_xor(v, 1); v += __shfl_xor(v, 2);
            v += __shfl_xor(v, 4); v += __shfl_xor(v, 8);
            den1[rg] = v;
        }
        // PV: o[r][dh] = qf @ cxT^T; divide by den; write
        #pragma unroll
        for (int rt = 0; rt < 2; ++rt){
            #pragma unroll
            for (int dt = 0; dt < 2; ++dt){
                f4 o = (f4){0.f,0.f,0.f,0.f};
                #pragma unroll
                for (int kk = 0; kk < 4; ++kk){
                    bh8 qa = *(const bh8*)&qw[(rt * 16 + m16) * CXP + kk * 32 + quad * 8];
                    o = __builtin_amdgcn_mfma_f32_16x16x32_bf16(qa, cxf[dt][kk], o, 0, 0, 0);
                }
                #pragma unroll
                for (int rg = 0; rg < 4; ++rg){
                    int r = rt * 16 + quad * 4 + rg;
                    if (r < rows){
                        float den = rt ? den1[rg] : den0[rg];
                        Ob[(rb + r) * D_ + hh * DH_ + dt * 16 + m16] = f2b(o[rg] / den);
                    }
                }
            }
        }
    }
}

// =============== final projection: out[b] = x[b,0] @ pw + pb (fp32) ===============
__global__ void k_final(const float* __restrict__ x, const float* __restrict__ pw,
                        const float* __restrict__ pb, float* __restrict__ out){
    int b = blockIdx.x, c = threadIdx.x;
    const float* xr = x + (size_t)b * NSEQ * D_;
    float s = pb[c];
    for (int k = 0; k < D_; ++k) s += xr[k] * pw[k * D_ + c];
    out[b * D_ + c] = s;
}

// =============== host launcher ===============
extern "C" void kernel_launch(void* const* d_in, const int* in_sizes, int n_in,
                              void* d_out, int out_size, void* d_ws, size_t ws_size,
                              hipStream_t stream){
    const float* expr   = (const float*)d_in[0];
    const float* tokemb = (const float*)d_in[1];
    const float* cls    = (const float*)d_in[2];
    const float* ln1g   = (const float*)d_in[3];
    const float* ln1b   = (const float*)d_in[4];
    const float* wq     = (const float*)d_in[5];
    const float* bq     = (const float*)d_in[6];
    const float* wk     = (const float*)d_in[7];
    const float* bk     = (const float*)d_in[8];
    const float* wv     = (const float*)d_in[9];
    const float* bv     = (const float*)d_in[10];
    const float* wo     = (const float*)d_in[11];
    const float* bo     = (const float*)d_in[12];
    const float* ln2g   = (const float*)d_in[13];
    const float* ln2b   = (const float*)d_in[14];
    const float* w1     = (const float*)d_in[15];
    const float* b1     = (const float*)d_in[16];
    const float* w2     = (const float*)d_in[17];
    const float* b2     = (const float*)d_in[18];
    const float* pw     = (const float*)d_in[19];
    const float* pb     = (const float*)d_in[20];
    const float* projs  = (const float*)d_in[21];
    float* out = (float*)d_out;

    float* ws = nullptr;
    if (ws_size >= WS_FLOATS * sizeof(float)) {
        ws = (float*)d_ws;
    } else {
        void* p = nullptr;
        hipGetSymbolAddress(&p, HIP_SYMBOL(g_ws));   // pure query, capture-safe
        ws = (float*)p;
    }

    float* x = ws;                                      // fp32 [NRP][256]
    unsigned short* hb = (unsigned short*)(x + SZP_);   // bf16 [NRP][256]
    unsigned short* qkvb = hb + (size_t)NRP_ * D_;      // bf16 [NRP][768]
    unsigned short* interb = qkvb + (size_t)NRP_ * QS_; // bf16 [NRP][1024]
    unsigned short* wqkvT = interb + (size_t)NRP_ * FF_;    // [6][768][256]
    unsigned short* woT = wqkvT + (size_t)L_ * QS_ * D_;    // [6][256][256]
    unsigned short* w1T = woT + (size_t)L_ * D_ * D_;       // [6][1024][256]
    unsigned short* w2T = w1T + (size_t)L_ * D_ * FF_;      // [6][256][1024]
    float* bqkv  = (float*)(w2T + (size_t)L_ * FF_ * D_);   // [6][768]
    float* diagk = bqkv + L_ * QS_ + 32;                    // [NR*8]
    float* ebuf  = diagk + (size_t)NR * 8 + 32;
    float* ssum  = ebuf + B_ * G_;
    unsigned* maxkey = (unsigned*)(ssum + 8);
    unsigned* stab   = maxkey + 8;
    float* kfsum = (float*)(stab + 8);                 // [BH_][M_]
    float* ctx   = kfsum + BH_ * M_ + 32;              // [BH_][M_][DH_]

    // weights: transpose + bf16 convert (QKV packed into [768][256] per layer)
    dim3 wb(32, 8);
    k_wconv<<<dim3(D_ / 32, D_ / 32, L_), wb, 0, stream>>>(wq, wqkvT,            D_, D_, QS_ * D_);
    k_wconv<<<dim3(D_ / 32, D_ / 32, L_), wb, 0, stream>>>(wk, wqkvT + 256 * D_, D_, D_, QS_ * D_);
    k_wconv<<<dim3(D_ / 32, D_ / 32, L_), wb, 0, stream>>>(wv, wqkvT + 512 * D_, D_, D_, QS_ * D_);
    k_wconv<<<dim3(D_ / 32, D_ / 32, L_), wb, 0, stream>>>(wo, woT, D_, D_, D_ * D_);
    k_wconv<<<dim3(FF_ / 32, D_ / 32, L_), wb, 0, stream>>>(w1, w1T, D_, FF_, D_ * FF_);
    k_wconv<<<dim3(D_ / 32, FF_ / 32, L_), wb, 0, stream>>>(w2, w2T, FF_, D_, FF_ * D_);
    k_packbias<<<L_, 256, 0, stream>>>(bq, bk, bv, bqkv);

    // preprocess
    k_pre_init<<<1, 64, 0, stream>>>(maxkey);
    k_rowsum<<<B_, 256, 0, stream>>>(expr, ssum);
    k_compute_e<<<(B_ * G_ + 255) / 256, 256, 0, stream>>>(expr, ssum, ebuf, maxkey);
    k_embed<<<NRP_, 256, 0, stream>>>(ebuf, maxkey, tokemb, cls, x);

    const int NYC = (NYT_ + 7) / 8;              // 67
    int gQKV = 8 * NYC * (QS_ / 128);            // 3216
    int gWO  = 8 * NYC * (D_ / 128);             // 1072
    int gF1  = 8 * NYC * (FF_ / 128);            // 4288
    int gF2  = 8 * NYC * (D_ / 128);             // 1072
    dim3 gBH((NSEQ + 255) / 256, 32);            // (67, 32)
    int gLN = NRP_ / 4;                          // 16928 (wave-per-row LN)

    for (int l = 0; l < L_; ++l){
        const float* pjl = projs + (size_t)l * M_ * DH_;
        k_ln<<<gLN, 256, 0, stream>>>(x, hb, ln1g + l * D_, ln1b + l * D_);
        gemm_bf16<3><<<gQKV, 256, 0, stream>>>(hb, wqkvT + (size_t)l * QS_ * D_, bqkv + l * QS_,
                                               nullptr, qkvb, D_, QS_, NYT_);
        k_layer_init<<<64, 256, 0, stream>>>(kfsum, ctx, stab);
        k_kmax<<<gBH, 256, 0, stream>>>(qkvb, pjl, stab, diagk);
        k_kv<<<gBH, 256, 0, stream>>>(qkvb, pjl, diagk, stab, kfsum, ctx);
        k_qattn<<<gBH, 256, 0, stream>>>(qkvb, pjl, kfsum, ctx, hb);   // hb := attn out
        gemm_bf16<1><<<gWO, 256, 0, stream>>>(hb, woT + (size_t)l * D_ * D_, bo + l * D_,
                                              x, nullptr, D_, D_, NYT_);
        k_ln<<<gLN, 256, 0, stream>>>(x, hb, ln2g + l * D_, ln2b + l * D_);
        gemm_bf16<2><<<gF1, 256, 0, stream>>>(hb, w1T + (size_t)l * D_ * FF_, b1 + l * FF_,
                                              nullptr, interb, D_, FF_, NYT_);
        gemm_bf16<1><<<gF2, 256, 0, stream>>>(interb, w2T + (size_t)l * FF_ * D_, b2 + l * D_,
                                              x, nullptr, FF_, D_, NYT_);
    }
    k_final<<<B_, 256, 0, stream>>>(x, pw, pb, out);
}

// Round 9
// 3326.215 us; speedup vs baseline: 1.1680x; 1.1680x over previous
//
#include <hip/hip_runtime.h>
#include <math.h>

#define B_ 4
#define G_ 16906
#define D_ 256
#define H_ 8
#define DH_ 32
#define M_ 110
#define L_ 6
#define FF_ 1024
#define NSEQ (G_ + 1)          // 16907
#define NR (B_ * NSEQ)         // 67628
#define NRP_ 67712             // 529*128, row-padded for 128-tiles
#define NYT_ 529               // row tiles
#define BH_ 32                 // B_*H_
#define QS_ 768                // fused qkv row stride (q:0, k:256, v:512)

static constexpr float SCALE_  = 0.42044820762685725f;   // 32^-0.25
static constexpr float MSCALE_ = 0.09534625892455922f;   // 110^-0.5
static constexpr float FEPS_   = 1e-4f;

// ---- static workspace (module-load-time allocation; R1 proved d_ws too small) ----
#define SZP_ ((size_t)NRP_ * D_)                 // fp32 x buffer
#define WS_FLOATS 92000000                       // ~368 MB
__device__ float g_ws[WS_FLOATS];

typedef __attribute__((ext_vector_type(8))) short bh8;   // 8 bf16 (4 VGPR)
typedef __attribute__((ext_vector_type(4))) float f4;    // MFMA acc

// ---- helpers ----
__device__ __forceinline__ unsigned f2u(float f){
    unsigned u = __float_as_uint(f);
    return (u & 0x80000000u) ? ~u : (u | 0x80000000u);
}
__device__ __forceinline__ float u2f(unsigned u){
    return (u & 0x80000000u) ? __uint_as_float(u & 0x7fffffffu) : __uint_as_float(~u);
}
__device__ __forceinline__ unsigned short f2b(float f){   // fp32 -> bf16 RNE
    unsigned u = __float_as_uint(f);
    return (unsigned short)((u + 0x7fffu + ((u >> 16) & 1u)) >> 16);
}
__device__ __forceinline__ float bf2f(unsigned short u){
    return __uint_as_float(((unsigned)u) << 16);
}
// R18: direct global->LDS DMA, 16B per lane (m97 ladder step; m151: +35% vs reg-staging)
__device__ __forceinline__ void gld16(const unsigned short* g, unsigned short* l){
    __builtin_amdgcn_global_load_lds((const __attribute__((address_space(1))) void*)g,
                                     (__attribute__((address_space(3))) void*)l, 16, 0, 0);
}

// =============== preprocess ===============
__global__ void k_pre_init(unsigned* __restrict__ maxkey){
    if (threadIdx.x == 0) *maxkey = 0x007fffffu;  // f2u(-inf)
}

__global__ void k_rowsum(const float* __restrict__ expr, float* __restrict__ ssum){
    int b = blockIdx.x, t = threadIdx.x;
    float s = 0.f;
    for (int g = t; g < G_; g += 256) s += fabsf(expr[(size_t)b * G_ + g]);
    __shared__ float red[256];
    red[t] = s; __syncthreads();
    for (int off = 128; off > 0; off >>= 1){ if (t < off) red[t] += red[t + off]; __syncthreads(); }
    if (t == 0) ssum[b] = red[0];
}

__global__ void k_compute_e(const float* __restrict__ expr, const float* __restrict__ ssum,
                            float* __restrict__ ebuf, unsigned* __restrict__ maxkey){
    int t = threadIdx.x;
    int idx = blockIdx.x * 256 + t;
    float e = -INFINITY;
    if (idx < B_ * G_){
        int b = idx / G_;
        float denom = fmaxf(ssum[b], 1e-12f);
        e = log1pf(expr[idx] / denom * 1e4f);
        ebuf[idx] = e;
    }
    __shared__ float red[256];
    red[t] = e; __syncthreads();
    for (int off = 128; off > 0; off >>= 1){ if (t < off) red[t] = fmaxf(red[t], red[t + off]); __syncthreads(); }
    if (t == 0) atomicMax(maxkey, f2u(red[0]));
}

__global__ void k_embed(const float* __restrict__ ebuf, const unsigned* __restrict__ maxkey,
                        const float* __restrict__ tokemb, const float* __restrict__ cls,
                        float* __restrict__ x){
    int row = blockIdx.x, t = threadIdx.x;
    if (row >= NR){ x[(size_t)row * D_ + t] = 0.f; return; }   // pad rows -> 0
    int b = row / NSEQ, i = row % NSEQ;
    float v;
    if (i == 0){
        v = cls[t];
    } else {
        float e = ebuf[(size_t)b * G_ + (i - 1)];
        float mx = u2f(*maxkey);
        float step = mx / 7.0f;                 // linspace(0,mx,8)[:7] = step*j
        int cnt = 0;
        #pragma unroll
        for (int j = 0; j < 7; ++j){
            float bin = step * (float)j;
            cnt += (bin < e) ? 1 : 0;           // searchsorted side='left'
        }
        if (cnt > 6) cnt = 6;
        v = tokemb[cnt * D_ + t];
    }
    x[(size_t)row * D_ + t] = v;
}

// =============== layernorm: fp32 in, bf16 out ===============
// R15: one 64-lane wave per row, shuffle-reduce — no barriers, no LDS.
__launch_bounds__(256)
__global__ void k_ln(const float* __restrict__ X, unsigned short* __restrict__ Y,
                     const float* __restrict__ g, const float* __restrict__ b){
    int wave = threadIdx.x >> 6, lane = threadIdx.x & 63;
    int row = blockIdx.x * 4 + wave;
    float4 v = *(const float4*)&X[(size_t)row * D_ + lane * 4];
    float s = v.x + v.y + v.z + v.w;
    s += __shfl_xor(s, 1);  s += __shfl_xor(s, 2);  s += __shfl_xor(s, 4);
    s += __shfl_xor(s, 8);  s += __shfl_xor(s, 16); s += __shfl_xor(s, 32);
    float mu = s * (1.0f / 256.0f);
    float d0 = v.x - mu, d1 = v.y - mu, d2 = v.z - mu, d3 = v.w - mu;
    float q = d0 * d0 + d1 * d1 + d2 * d2 + d3 * d3;
    q += __shfl_xor(q, 1);  q += __shfl_xor(q, 2);  q += __shfl_xor(q, 4);
    q += __shfl_xor(q, 8);  q += __shfl_xor(q, 16); q += __shfl_xor(q, 32);
    float inv = rsqrtf(q * (1.0f / 256.0f) + 1e-5f);
    float4 gv = *(const float4*)&g[lane * 4];
    float4 bv = *(const float4*)&b[lane * 4];
    ushort4 o;
    o.x = f2b(d0 * inv * gv.x + bv.x);
    o.y = f2b(d1 * inv * gv.y + bv.y);
    o.z = f2b(d2 * inv * gv.z + bv.z);
    o.w = f2b(d3 * inv * gv.w + bv.w);
    *(ushort4*)&Y[(size_t)row * D_ + lane * 4] = o;
}

// =============== weight transpose + bf16 convert: Wout[n][k] = Win[k][n] ===============
__global__ void k_wconv(const float* __restrict__ Win, unsigned short* __restrict__ Wout,
                        int K, int N, int lstride){
    __shared__ float tile[32][33];
    int l = blockIdx.z;
    const float* W = Win + (size_t)l * K * N;
    unsigned short* O = Wout + (size_t)l * lstride;
    int n0 = blockIdx.x * 32, k0 = blockIdx.y * 32;
    int tx = threadIdx.x, ty = threadIdx.y;
    #pragma unroll
    for (int j = 0; j < 4; ++j)
        tile[ty + j * 8][tx] = W[(size_t)(k0 + ty + j * 8) * N + n0 + tx];
    __syncthreads();
    #pragma unroll
    for (int j = 0; j < 4; ++j){
        int n = ty + j * 8;
        O[(size_t)(n0 + n) * K + k0 + tx] = f2b(tile[tx][n]);
    }
}

__global__ void k_packbias(const float* __restrict__ bq, const float* __restrict__ bk,
                           const float* __restrict__ bv, float* __restrict__ o){
    int l = blockIdx.x, t = threadIdx.x;
    o[l * QS_ + t]        = bq[l * D_ + t];
    o[l * QS_ + 256 + t]  = bk[l * D_ + t];
    o[l * QS_ + 512 + t]  = bv[l * D_ + t];
}

// =============== bf16 MFMA GEMM: C = op(A @ Wt^T + bias) ===============
// MODE 0: Cf = A@W + bias (fp32)        MODE 1: Cf += A@W + bias (fp32 residual)
// MODE 2: Cb = bf16(gelu(A@W + bias))   MODE 3: Cb = bf16(A@W + bias)
// R18/R23: m97 structure — global_load_lds(16B) direct staging, linear [128][32]
//      LDS, chunk-XOR swizzle via pre-swizzled GLOBAL source (m173) + matching
//      ds_read swizzle (2-way banks = free). 32 KB LDS => 5 blocks/CU.
//      R22's 3-buffer counted-vmcnt pipeline MEASURED WORSE (157 vs 120 µs,
//      FETCH +40%): K=256 = 8 iters is prologue-dominated and L2-A-panel-reuse
//      sensitive — T4's regime (K>=4096) doesn't apply. Keep 1-deep dbuf.
#define ABUF_SH 4096           // one 128x32 bf16 tile, in shorts (8 KB)
#define BUFS_SH 8192           // A tile + B tile per stage, in shorts (16 KB)
#define EPIT 136
template <int MODE>
__launch_bounds__(256)
__global__ void gemm_bf16(const unsigned short* __restrict__ A,
                          const unsigned short* __restrict__ Wt,
                          const float* __restrict__ bias,
                          float* __restrict__ Cf, unsigned short* __restrict__ Cb,
                          int K, int N, int NY){
    int NX = N >> 7;
    int lid = blockIdx.x;
    int xcd = lid & 7, slot = lid >> 3;
    int colt = slot % NX;
    int rowt = (slot / NX) * 8 + xcd;
    if (rowt >= NY) return;
    int rowBase = rowt * 128, colBase = colt * 128;

    __shared__ __align__(16) unsigned short smem[2 * BUFS_SH];   // 32 KB
    int tid = threadIdx.x;
    int lane = tid & 63, wave = tid >> 6;
    int wrow = (wave >> 1) * 64, wcol = (wave & 1) * 64;
    int m = lane & 15, kg = lane >> 4;

    // staging: thread t owns LDS slot (row = t>>2, 16B-chunk c = t&3), dest is
    // linear (base + t*16B). Slot (r,c) holds GLOBAL chunk c ^ ((r>>1)&3).
    int sr = tid >> 2, sc = tid & 3;
    int scs = sc ^ ((sr >> 1) & 3);
    const unsigned short* Ag = A  + (size_t)(rowBase + sr) * K + scs * 8;
    const unsigned short* Bg = Wt + (size_t)(colBase + sr) * K + scs * 8;
    // read-side swizzle: want chunk kg of row (..+m); base row mult of 16 -> use m only
    int kc8 = (kg ^ ((m >> 1) & 3)) * 8;

    f4 acc[4][4];
    #pragma unroll
    for (int i = 0; i < 4; ++i)
        #pragma unroll
        for (int j = 0; j < 4; ++j) acc[i][j] = (f4){0.f, 0.f, 0.f, 0.f};

    auto stage = [&](int sel, int it){
        unsigned short* sb = smem + (sel ? BUFS_SH : 0);
        int k0 = it << 5;
        gld16(Ag + k0,                  sb + (tid << 3));
        gld16(Ag + (size_t)64 * K + k0, sb + 2048 + (tid << 3));
        gld16(Bg + k0,                  sb + ABUF_SH + (tid << 3));
        gld16(Bg + (size_t)64 * K + k0, sb + ABUF_SH + 2048 + (tid << 3));
    };

    stage(0, 0);
    const int NIT = K >> 5;
    for (int it = 0; it < NIT; ++it){
        int cur = (it & 1) ? BUFS_SH : 0;
        __syncthreads();                       // drains vmcnt -> buf[cur] ready
        if (it + 1 < NIT) stage((it + 1) & 1, it + 1);   // in flight across this iter
        bh8 af[4], bf[4];
        #pragma unroll
        for (int mi = 0; mi < 4; ++mi)
            af[mi] = *(const bh8*)&smem[cur + (wrow + mi * 16 + m) * 32 + kc8];
        #pragma unroll
        for (int ni = 0; ni < 4; ++ni)
            bf[ni] = *(const bh8*)&smem[cur + ABUF_SH + (wcol + ni * 16 + m) * 32 + kc8];
        #pragma unroll
        for (int mi = 0; mi < 4; ++mi)
            #pragma unroll
            for (int ni = 0; ni < 4; ++ni)
                acc[mi][ni] = __builtin_amdgcn_mfma_f32_16x16x32_bf16(af[mi], bf[ni], acc[mi][ni], 0, 0, 0);
    }
    __syncthreads();
    int q4 = lane >> 4;
    if (MODE == 0 || MODE == 1){
        #pragma unroll
        for (int ni = 0; ni < 4; ++ni){
            int col = colBase + wcol + ni * 16 + m;
            float bv = bias[col];
            #pragma unroll
            for (int mi = 0; mi < 4; ++mi){
                int r0 = rowBase + wrow + mi * 16 + q4 * 4;
                #pragma unroll
                for (int rg = 0; rg < 4; ++rg){
                    int row = r0 + rg;
                    float v = acc[mi][ni][rg] + bv;
                    if (MODE == 1) v += Cf[(size_t)row * N + col];
                    Cf[(size_t)row * N + col] = v;
                }
            }
        }
    } else {
        #pragma unroll
        for (int half = 0; half < 2; ++half){
            if ((wrow >> 6) == half){
                #pragma unroll
                for (int ni = 0; ni < 4; ++ni){
                    int coll = wcol + ni * 16 + m;
                    float bv = bias[colBase + coll];
                    #pragma unroll
                    for (int mi = 0; mi < 4; ++mi){
                        int rl0 = (wrow & 63) + mi * 16 + q4 * 4;
                        #pragma unroll
                        for (int rg = 0; rg < 4; ++rg){
                            float v = acc[mi][ni][rg] + bv;
                            if (MODE == 2) v = 0.5f * v * (1.0f + erff(v * 0.70710678118654752f));
                            smem[(rl0 + rg) * EPIT + coll] = f2b(v);
                        }
                    }
                }
            }
            __syncthreads();
            #pragma unroll
            for (int p = 0; p < 4; ++p){
                int idx = p * 256 + tid;
                int r = idx >> 4, ch = idx & 15;
                int grow = rowBase + half * 64 + r;
                uint4 val = *(const uint4*)&smem[r * EPIT + ch * 8];
                *(uint4*)&Cb[(size_t)grow * N + colBase + ch * 8] = val;
            }
            __syncthreads();
        }
    }
}

// =============== attention state init ===============
__global__ void k_layer_init(float* __restrict__ kfsum, float* __restrict__ ctx,
                             unsigned* __restrict__ stab){
    int t = blockIdx.x * 256 + threadIdx.x;
    int nt = gridDim.x * 256;
    if (t == 0) *stab = 0x007fffffu;  // f2u(-inf)
    for (int i = t; i < BH_ * M_; i += nt) kfsum[i] = 0.f;
    for (int i = t; i < BH_ * M_ * DH_; i += nt) ctx[i] = 0.f;
}

// ---- k_kmax (R19 per-wave structure + R21 diagk restored from register frags) ----
__launch_bounds__(256)
__global__ void k_kmax(const unsigned short* __restrict__ qkv, const float* __restrict__ proj,
                       unsigned* __restrict__ stab, float* __restrict__ diagk){
    __shared__ __align__(16) unsigned short pjT[112 * 40];
    __shared__ float red[256];
    int t = threadIdx.x, lane = t & 63, wave = t >> 6;
    int m16 = lane & 15, quad = lane >> 4;
    int bh = blockIdx.y, b = bh >> 3, hh = bh & 7;
    for (int e = t; e < 112 * 32; e += 256){
        int mm = e >> 5, d = e & 31;
        pjT[mm * 40 + d] = f2b((mm < M_) ? SCALE_ * proj[mm * DH_ + d] : 0.f);
    }
    __syncthreads();
    bh8 pj[7];
    #pragma unroll
    for (int nt = 0; nt < 7; ++nt)
        pj[nt] = *(const bh8*)&pjT[(nt * 16 + m16) * 40 + quad * 8];
    int i0 = blockIdx.x * 256, i1 = min(i0 + 256, NSEQ);
    float mx = -INFINITY;
    for (int t0 = i0 + wave * 32; t0 < i1; t0 += 128){
        int rows = min(32, i1 - t0);
        size_t rb = (size_t)(b * NSEQ + t0);
        bh8 a0 = *(const bh8*)(qkv + (rb + m16) * QS_ + 256 + hh * DH_ + quad * 8);
        bh8 a1 = *(const bh8*)(qkv + (rb + 16 + m16) * QS_ + 256 + hh * DH_ + quad * 8);
        // R21: diagk from register fragments (per-lane 8-elem sum + shfl over quads)
        {
            float s0 = 0.f, s1 = 0.f;
            const unsigned short* p0 = (const unsigned short*)&a0;
            const unsigned short* p1 = (const unsigned short*)&a1;
            #pragma unroll
            for (int j = 0; j < 8; ++j){
                float x0 = bf2f(p0[j]); s0 += x0 * x0;
                float x1 = bf2f(p1[j]); s1 += x1 * x1;
            }
            s0 += __shfl_xor(s0, 16); s0 += __shfl_xor(s0, 32);
            s1 += __shfl_xor(s1, 16); s1 += __shfl_xor(s1, 32);
            if (quad == 0){
                if (m16 < rows)
                    diagk[(rb + m16) * 8 + hh]      = 0.5f * SCALE_ * SCALE_ * s0;
                if (16 + m16 < rows)
                    diagk[(rb + 16 + m16) * 8 + hh] = 0.5f * SCALE_ * SCALE_ * s1;
            }
        }
        #pragma unroll
        for (int nt = 0; nt < 7; ++nt){
            int f = nt * 16 + m16;
            f4 d0 = (f4){0.f,0.f,0.f,0.f}, d1 = (f4){0.f,0.f,0.f,0.f};
            d0 = __builtin_amdgcn_mfma_f32_16x16x32_bf16(a0, pj[nt], d0, 0, 0, 0);
            d1 = __builtin_amdgcn_mfma_f32_16x16x32_bf16(a1, pj[nt], d1, 0, 0, 0);
            if (f < M_){
                #pragma unroll
                for (int rg = 0; rg < 4; ++rg){
                    int r0 = quad * 4 + rg;
                    if (r0 < rows)      mx = fmaxf(mx, d0[rg]);
                    if (r0 + 16 < rows) mx = fmaxf(mx, d1[rg]);
                }
            }
        }
    }
    red[t] = mx; __syncthreads();
    for (int off = 128; off > 0; off >>= 1){ if (t < off) red[t] = fmaxf(red[t], red[t + off]); __syncthreads(); }
    if (t == 0) atomicMax(stab, f2u(red[0]));
}

// ---- k_kv: R0 block-cooperative version (proven ≤146 µs; R19/R20 per-wave
// rewrites measured 238/247 µs — reverted, see R21 post-mortem) ----
__launch_bounds__(256)
__global__ void k_kv(const unsigned short* __restrict__ qkv,
                     const float* __restrict__ proj, const float* __restrict__ diagk,
                     const unsigned* __restrict__ stabkey,
                     float* __restrict__ kfsum, float* __restrict__ ctx){
    __shared__ __align__(16) unsigned short pjT[112 * 40];
    __shared__ __align__(16) unsigned short kl[32 * 40];
    __shared__ __align__(16) unsigned short vT[32 * 40];
    __shared__ __align__(16) unsigned short kfT[112 * 40];
    __shared__ float diagl[32];
    int t = threadIdx.x, lane = t & 63, wave = t >> 6;
    int m16 = lane & 15, quad = lane >> 4;
    int bh = blockIdx.y, b = bh >> 3, hh = bh & 7;
    for (int e = t; e < 112 * 32; e += 256){
        int mm = e >> 5, d = e & 31;
        pjT[mm * 40 + d] = f2b((mm < M_) ? SCALE_ * proj[mm * DH_ + d] : 0.f);
    }
    float stab = u2f(*stabkey);
    f4 acc[2][2];
    #pragma unroll
    for (int i = 0; i < 2; ++i)
        #pragma unroll
        for (int j = 0; j < 2; ++j) acc[i][j] = (f4){0.f,0.f,0.f,0.f};
    float ksum = 0.f;
    int i0 = blockIdx.x * 256, i1 = min(i0 + 256, NSEQ);
    int sr = t >> 2, sl = t & 3;
    __syncthreads();
    for (int t0 = i0; t0 < i1; t0 += 32){
        int rows = min(32, i1 - t0);
        if (t < 128){
            size_t base = ((size_t)(b * NSEQ + t0 + sr)) * QS_ + hh * DH_ + sl * 8;
            uint4 kv = (uint4){0,0,0,0}, vv = (uint4){0,0,0,0};
            if (sr < rows){
                kv = *(const uint4*)(qkv + base + 256);
                vv = *(const uint4*)(qkv + base + 512);
            }
            *(uint4*)&kl[sr * 40 + sl * 8] = kv;
            const unsigned short* vs = (const unsigned short*)&vv;
            #pragma unroll
            for (int j = 0; j < 8; ++j)
                vT[(sl * 8 + j) * 40 + sr] = vs[j];
        }
        if (t < 32) diagl[t] = (t < rows) ? diagk[((size_t)(b * NSEQ + t0 + t)) * 8 + hh] : 0.f;
        __syncthreads();
        #pragma unroll
        for (int nn = 0; nn < 2; ++nn){
            int nt = wave + nn * 4;
            if (nt >= 7) continue;
            bh8 bfrag = *(const bh8*)&pjT[(nt * 16 + m16) * 40 + quad * 8];
            int f = nt * 16 + m16;
            #pragma unroll
            for (int mt = 0; mt < 2; ++mt){
                bh8 afrag = *(const bh8*)&kl[(mt * 16 + m16) * 40 + quad * 8];
                f4 dd = (f4){0.f,0.f,0.f,0.f};
                dd = __builtin_amdgcn_mfma_f32_16x16x32_bf16(afrag, bfrag, dd, 0, 0, 0);
                #pragma unroll
                for (int rg = 0; rg < 4; ++rg){
                    int r = mt * 16 + quad * 4 + rg;
                    float kf = 0.f;
                    if (r < rows) kf = MSCALE_ * (__expf(dd[rg] - diagl[r] - stab) + FEPS_);
                    kfT[f * 40 + r] = f2b(kf);
                }
            }
        }
        __syncthreads();
        #pragma unroll
        for (int mm = 0; mm < 2; ++mm){
            int mt = wave + mm * 4;
            if (mt >= 7) continue;
            bh8 afrag = *(const bh8*)&kfT[(mt * 16 + m16) * 40 + quad * 8];
            #pragma unroll
            for (int nt2 = 0; nt2 < 2; ++nt2){
                bh8 bfrag = *(const bh8*)&vT[(nt2 * 16 + m16) * 40 + quad * 8];
                acc[mm][nt2] = __builtin_amdgcn_mfma_f32_16x16x32_bf16(afrag, bfrag, acc[mm][nt2], 0, 0, 0);
            }
        }
        if (t < M_){
            for (int i = 0; i < rows; ++i) ksum += bf2f(kfT[t * 40 + i]);
        }
        __syncthreads();
    }
    float* ctx_bh = ctx + (size_t)bh * M_ * DH_;
    #pragma unroll
    for (int mm = 0; mm < 2; ++mm){
        int mt = wave + mm * 4;
        if (mt >= 7) continue;
        #pragma unroll
        for (int nt2 = 0; nt2 < 2; ++nt2){
            #pragma unroll
            for (int rg = 0; rg < 4; ++rg){
                int f = mt * 16 + quad * 4 + rg;
                int dh = nt2 * 16 + m16;
                if (f < M_) atomicAdd(&ctx_bh[f * DH_ + dh], acc[mm][nt2][rg]);
            }
        }
    }
    if (t < M_) atomicAdd(&kfsum[bh * M_ + t], ksum);
}

// ---- k_qattn: R19 per-wave version (rowmax via shfl, wave-private qf slab,
// no inner barriers) ----
#define CXP 136
__launch_bounds__(256)
__global__ void k_qattn(const unsigned short* __restrict__ qkv, const float* __restrict__ proj,
                        const float* __restrict__ kfsumg,
                        const float* __restrict__ ctxg, unsigned short* __restrict__ Ob){
    __shared__ __align__(16) unsigned short pjT[112 * 40];
    __shared__ __align__(16) unsigned short cxT[32 * CXP];     // [dh][f], zero-padded f>=M_
    __shared__ __align__(16) unsigned short qfs[4][32 * CXP];  // per-wave qf slab
    int t = threadIdx.x, lane = t & 63, wave = t >> 6;
    int m16 = lane & 15, quad = lane >> 4;
    int bh = blockIdx.y, b = bh >> 3, hh = bh & 7;
    const float* ctx_bh = ctxg + (size_t)bh * M_ * DH_;
    for (int e = t; e < 112 * 32; e += 256){
        int mm = e >> 5, d = e & 31;
        pjT[mm * 40 + d] = f2b((mm < M_) ? SCALE_ * proj[mm * DH_ + d] : 0.f);
    }
    for (int e = t; e < 32 * 128; e += 256){
        int dh = e >> 7, f = e & 127;
        cxT[dh * CXP + f] = f2b((f < M_) ? ctx_bh[f * DH_ + dh] : 0.f);
    }
    // zero qf slab cols 112..127 once (never written by f-tiles; avoids NaN garbage)
    {
        unsigned short* qw = &qfs[wave][0];
        int r = lane & 31, c0 = 112 + (lane >> 5) * 8;
        #pragma unroll
        for (int j = 0; j < 8; ++j) qw[r * CXP + c0 + j] = 0;
    }
    __syncthreads();
    float kfsr[7];
    #pragma unroll
    for (int nt = 0; nt < 7; ++nt){
        int f = nt * 16 + m16;
        kfsr[nt] = (f < M_) ? kfsumg[bh * M_ + f] : 0.f;
    }
    bh8 cxf[2][4];
    #pragma unroll
    for (int dt = 0; dt < 2; ++dt)
        #pragma unroll
        for (int kk = 0; kk < 4; ++kk)
            cxf[dt][kk] = *(const bh8*)&cxT[(dt * 16 + m16) * CXP + kk * 32 + quad * 8];
    unsigned short* qw = &qfs[wave][0];
    int i0 = blockIdx.x * 256, i1 = min(i0 + 256, NSEQ);
    for (int t0 = i0 + wave * 32; t0 < i1; t0 += 128){
        int rows = min(32, i1 - t0);
        size_t rb = (size_t)(b * NSEQ + t0);
        bh8 a0 = *(const bh8*)(qkv + (rb + m16) * QS_ + hh * DH_ + quad * 8);
        bh8 a1 = *(const bh8*)(qkv + (rb + 16 + m16) * QS_ + hh * DH_ + quad * 8);
        float s0 = 0.f, s1 = 0.f;
        {
            const unsigned short* p0 = (const unsigned short*)&a0;
            const unsigned short* p1 = (const unsigned short*)&a1;
            #pragma unroll
            for (int j = 0; j < 8; ++j){
                float x0 = bf2f(p0[j]); s0 += x0 * x0;
                float x1 = bf2f(p1[j]); s1 += x1 * x1;
            }
            s0 += __shfl_xor(s0, 16); s0 += __shfl_xor(s0, 32);
            s1 += __shfl_xor(s1, 16); s1 += __shfl_xor(s1, 32);
            s0 *= 0.5f * SCALE_ * SCALE_;
            s1 *= 0.5f * SCALE_ * SCALE_;
        }
        f4 dv0[7], dv1[7];
        #pragma unroll
        for (int nt = 0; nt < 7; ++nt){
            bh8 pjf = *(const bh8*)&pjT[(nt * 16 + m16) * 40 + quad * 8];
            f4 d0 = (f4){0.f,0.f,0.f,0.f}, d1 = (f4){0.f,0.f,0.f,0.f};
            dv0[nt] = __builtin_amdgcn_mfma_f32_16x16x32_bf16(a0, pjf, d0, 0, 0, 0);
            dv1[nt] = __builtin_amdgcn_mfma_f32_16x16x32_bf16(a1, pjf, d1, 0, 0, 0);
        }
        // per-row max over f: in-lane over nt (guard f<M_), then shfl over m16
        float rm0[4], rm1[4];
        #pragma unroll
        for (int rg = 0; rg < 4; ++rg){ rm0[rg] = -INFINITY; rm1[rg] = -INFINITY; }
        #pragma unroll
        for (int nt = 0; nt < 7; ++nt){
            if (nt * 16 + m16 < M_){
                #pragma unroll
                for (int rg = 0; rg < 4; ++rg){
                    rm0[rg] = fmaxf(rm0[rg], dv0[nt][rg]);
                    rm1[rg] = fmaxf(rm1[rg], dv1[nt][rg]);
                }
            }
        }
        #pragma unroll
        for (int rg = 0; rg < 4; ++rg){
            float v = rm0[rg];
            v = fmaxf(v, __shfl_xor(v, 1)); v = fmaxf(v, __shfl_xor(v, 2));
            v = fmaxf(v, __shfl_xor(v, 4)); v = fmaxf(v, __shfl_xor(v, 8));
            rm0[rg] = v;
            v = rm1[rg];
            v = fmaxf(v, __shfl_xor(v, 1)); v = fmaxf(v, __shfl_xor(v, 2));
            v = fmaxf(v, __shfl_xor(v, 4)); v = fmaxf(v, __shfl_xor(v, 8));
            rm1[rg] = v;
        }
        float dg0[4], dg1[4];
        #pragma unroll
        for (int rg = 0; rg < 4; ++rg){
            dg0[rg] = __shfl(s0, quad * 4 + rg);
            dg1[rg] = __shfl(s1, quad * 4 + rg);
        }
        // qf -> slab [r][f]; den partials in-lane
        float den0[4], den1[4];
        #pragma unroll
        for (int rg = 0; rg < 4; ++rg){ den0[rg] = 0.f; den1[rg] = 0.f; }
        #pragma unroll
        for (int nt = 0; nt < 7; ++nt){
            int f = nt * 16 + m16;
            #pragma unroll
            for (int rg = 0; rg < 4; ++rg){
                int r0 = quad * 4 + rg;
                float q0 = 0.f, q1 = 0.f;
                if (f < M_){
                    q0 = MSCALE_ * (__expf(dv0[nt][rg] - dg0[rg] - rm0[rg]) + FEPS_);
                    q1 = MSCALE_ * (__expf(dv1[nt][rg] - dg1[rg] - rm1[rg]) + FEPS_);
                }
                qw[r0 * CXP + f]        = f2b(q0);
                qw[(16 + r0) * CXP + f] = f2b(q1);
                den0[rg] += q0 * kfsr[nt];
                den1[rg] += q1 * kfsr[nt];
            }
        }
        #pragma unroll
        for (int rg = 0; rg < 4; ++rg){
            float v = den0[rg];
            v += __shfl_xor(v, 1); v += __shfl_xor(v, 2);
            v += __shfl_xor(v, 4); v += __shfl_xor(v, 8);
            den0[rg] = v;
            v = den1[rg];
            v += __shfl_xor(v, 1); v += __shfl_xor(v, 2);
            v += __shfl_xor(v, 4); v += __shfl_xor(v, 8);
            den1[rg] = v;
        }
        // PV: o[r][dh] = qf @ cxT^T; divide by den; write
        #pragma unroll
        for (int rt = 0; rt < 2; ++rt){
            #pragma unroll
            for (int dt = 0; dt < 2; ++dt){
                f4 o = (f4){0.f,0.f,0.f,0.f};
                #pragma unroll
                for (int kk = 0; kk < 4; ++kk){
                    bh8 qa = *(const bh8*)&qw[(rt * 16 + m16) * CXP + kk * 32 + quad * 8];
                    o = __builtin_amdgcn_mfma_f32_16x16x32_bf16(qa, cxf[dt][kk], o, 0, 0, 0);
                }
                #pragma unroll
                for (int rg = 0; rg < 4; ++rg){
                    int r = rt * 16 + quad * 4 + rg;
                    if (r < rows){
                        float den = rt ? den1[rg] : den0[rg];
                        Ob[(rb + r) * D_ + hh * DH_ + dt * 16 + m16] = f2b(o[rg] / den);
                    }
                }
            }
        }
    }
}

// =============== final projection: out[b] = x[b,0] @ pw + pb (fp32) ===============
__global__ void k_final(const float* __restrict__ x, const float* __restrict__ pw,
                        const float* __restrict__ pb, float* __restrict__ out){
    int b = blockIdx.x, c = threadIdx.x;
    const float* xr = x + (size_t)b * NSEQ * D_;
    float s = pb[c];
    for (int k = 0; k < D_; ++k) s += xr[k] * pw[k * D_ + c];
    out[b * D_ + c] = s;
}

// =============== host launcher ===============
extern "C" void kernel_launch(void* const* d_in, const int* in_sizes, int n_in,
                              void* d_out, int out_size, void* d_ws, size_t ws_size,
                              hipStream_t stream){
    const float* expr   = (const float*)d_in[0];
    const float* tokemb = (const float*)d_in[1];
    const float* cls    = (const float*)d_in[2];
    const float* ln1g   = (const float*)d_in[3];
    const float* ln1b   = (const float*)d_in[4];
    const float* wq     = (const float*)d_in[5];
    const float* bq     = (const float*)d_in[6];
    const float* wk     = (const float*)d_in[7];
    const float* bk     = (const float*)d_in[8];
    const float* wv     = (const float*)d_in[9];
    const float* bv     = (const float*)d_in[10];
    const float* wo     = (const float*)d_in[11];
    const float* bo     = (const float*)d_in[12];
    const float* ln2g   = (const float*)d_in[13];
    const float* ln2b   = (const float*)d_in[14];
    const float* w1     = (const float*)d_in[15];
    const float* b1     = (const float*)d_in[16];
    const float* w2     = (const float*)d_in[17];
    const float* b2     = (const float*)d_in[18];
    const float* pw     = (const float*)d_in[19];
    const float* pb     = (const float*)d_in[20];
    const float* projs  = (const float*)d_in[21];
    float* out = (float*)d_out;

    float* ws = nullptr;
    if (ws_size >= WS_FLOATS * sizeof(float)) {
        ws = (float*)d_ws;
    } else {
        void* p = nullptr;
        hipGetSymbolAddress(&p, HIP_SYMBOL(g_ws));   // pure query, capture-safe
        ws = (float*)p;
    }

    float* x = ws;                                      // fp32 [NRP][256]
    unsigned short* hb = (unsigned short*)(x + SZP_);   // bf16 [NRP][256]
    unsigned short* qkvb = hb + (size_t)NRP_ * D_;      // bf16 [NRP][768]
    unsigned short* interb = qkvb + (size_t)NRP_ * QS_; // bf16 [NRP][1024]
    unsigned short* wqkvT = interb + (size_t)NRP_ * FF_;    // [6][768][256]
    unsigned short* woT = wqkvT + (size_t)L_ * QS_ * D_;    // [6][256][256]
    unsigned short* w1T = woT + (size_t)L_ * D_ * D_;       // [6][1024][256]
    unsigned short* w2T = w1T + (size_t)L_ * D_ * FF_;      // [6][256][1024]
    float* bqkv  = (float*)(w2T + (size_t)L_ * FF_ * D_);   // [6][768]
    float* diagk = bqkv + L_ * QS_ + 32;                    // [NR*8]
    float* ebuf  = diagk + (size_t)NR * 8 + 32;
    float* ssum  = ebuf + B_ * G_;
    unsigned* maxkey = (unsigned*)(ssum + 8);
    unsigned* stab   = maxkey + 8;
    float* kfsum = (float*)(stab + 8);                 // [BH_][M_]
    float* ctx   = kfsum + BH_ * M_ + 32;              // [BH_][M_][DH_]

    // weights: transpose + bf16 convert (QKV packed into [768][256] per layer)
    dim3 wb(32, 8);
    k_wconv<<<dim3(D_ / 32, D_ / 32, L_), wb, 0, stream>>>(wq, wqkvT,            D_, D_, QS_ * D_);
    k_wconv<<<dim3(D_ / 32, D_ / 32, L_), wb, 0, stream>>>(wk, wqkvT + 256 * D_, D_, D_, QS_ * D_);
    k_wconv<<<dim3(D_ / 32, D_ / 32, L_), wb, 0, stream>>>(wv, wqkvT + 512 * D_, D_, D_, QS_ * D_);
    k_wconv<<<dim3(D_ / 32, D_ / 32, L_), wb, 0, stream>>>(wo, woT, D_, D_, D_ * D_);
    k_wconv<<<dim3(FF_ / 32, D_ / 32, L_), wb, 0, stream>>>(w1, w1T, D_, FF_, D_ * FF_);
    k_wconv<<<dim3(D_ / 32, FF_ / 32, L_), wb, 0, stream>>>(w2, w2T, FF_, D_, FF_ * D_);
    k_packbias<<<L_, 256, 0, stream>>>(bq, bk, bv, bqkv);

    // preprocess
    k_pre_init<<<1, 64, 0, stream>>>(maxkey);
    k_rowsum<<<B_, 256, 0, stream>>>(expr, ssum);
    k_compute_e<<<(B_ * G_ + 255) / 256, 256, 0, stream>>>(expr, ssum, ebuf, maxkey);
    k_embed<<<NRP_, 256, 0, stream>>>(ebuf, maxkey, tokemb, cls, x);

    const int NYC = (NYT_ + 7) / 8;              // 67
    int gQKV = 8 * NYC * (QS_ / 128);            // 3216
    int gWO  = 8 * NYC * (D_ / 128);             // 1072
    int gF1  = 8 * NYC * (FF_ / 128);            // 4288
    int gF2  = 8 * NYC * (D_ / 128);             // 1072
    dim3 gBH((NSEQ + 255) / 256, 32);            // (67, 32)
    int gLN = NRP_ / 4;                          // 16928 (wave-per-row LN)

    for (int l = 0; l < L_; ++l){
        const float* pjl = projs + (size_t)l * M_ * DH_;
        k_ln<<<gLN, 256, 0, stream>>>(x, hb, ln1g + l * D_, ln1b + l * D_);
        gemm_bf16<3><<<gQKV, 256, 0, stream>>>(hb, wqkvT + (size_t)l * QS_ * D_, bqkv + l * QS_,
                                               nullptr, qkvb, D_, QS_, NYT_);
        k_layer_init<<<64, 256, 0, stream>>>(kfsum, ctx, stab);
        k_kmax<<<gBH, 256, 0, stream>>>(qkvb, pjl, stab, diagk);
        k_kv<<<gBH, 256, 0, stream>>>(qkvb, pjl, diagk, stab, kfsum, ctx);
        k_qattn<<<gBH, 256, 0, stream>>>(qkvb, pjl, kfsum, ctx, hb);   // hb := attn out
        gemm_bf16<1><<<gWO, 256, 0, stream>>>(hb, woT + (size_t)l * D_ * D_, bo + l * D_,
                                              x, nullptr, D_, D_, NYT_);
        k_ln<<<gLN, 256, 0, stream>>>(x, hb, ln2g + l * D_, ln2b + l * D_);
        gemm_bf16<2><<<gF1, 256, 0, stream>>>(hb, w1T + (size_t)l * D_ * FF_, b1 + l * FF_,
                                              nullptr, interb, D_, FF_, NYT_);
        gemm_bf16<1><<<gF2, 256, 0, stream>>>(interb, w2T + (size_t)l * FF_ * D_, b2 + l * D_,
                                              x, nullptr, FF_, D_, NYT_);
    }
    k_final<<<B_, 256, 0, stream>>>(x, pw, pb, out);
}